// Round 5
// baseline (374.703 us; speedup 1.0000x reference)
//
#include <hip/hip_runtime.h>
#include <math.h>
#include <stdint.h>

// ArmInt via MFMA, R5: v_perm bf16 packing + dropped negligible chunks +
// 2 row-tiles per wave (software pipelining / latency hiding).
//
// R4 post-mortem: kernel ~114us but issue-cost math says ~40us -> latency-
// exposed (x-load ~900cyc + 2 LDS round-trips) at low occupancy, plus fat
// split code (per-short vector inserts). R5:
//  (a) all f32->bf16x8 fragment builds via __builtin_amdgcn_perm: 1 inst per
//      2 shorts (top-half gather), frags built as uint4 and bitcast.
//  (b) error-budget pruning (threshold 6.5 quanta, measured 1): drop a2 (3rd
//      x chunk; |err| rms ~5e-4 vs boundary spacing 1), a1*W0lo and c1*W1lo
//      (only diagonal entries of Wlo are nonzero; |err| <= 0.03 on one term).
//      Layers 1/out otherwise exact in fp32 (all terms multiples of 2^-8,
//      magnitudes < 2^23). Layer0 keeps a0/a1 vs W0hi + a0*W0lo.
//  (c) 2 tiles (64 rows) per wave, straight-line interleaved: tile-1 work
//      fills tile-0 VMEM/DS latency. LDS 2x4608B/wave = 36.9KB/block.
//
// MFMA 16x16x32 layouts (verified R3/R4):
//   A: lane holds A[m=lane&15][k=(lane>>4)*8+j]
//   B: lane holds B[k=(lane>>4)*8+j][n=lane&15]  (= W[n][k], K-contiguous)
//   C/D: col=lane&15, row=(lane>>4)*4+reg
// All LDS deps intra-wave (lockstep + in-order DS) -> no __syncthreads.

typedef __attribute__((ext_vector_type(8))) short bf16x8;
typedef __attribute__((ext_vector_type(4))) float f32x4;

#define MFMA16(A, B, C) __builtin_amdgcn_mfma_f32_16x16x32_bf16((A), (B), (C), 0, 0, 0)

__device__ inline float bf_topf(float v) {             // top bf16 chunk as fp32
    return __uint_as_float(__float_as_uint(v) & 0xffff0000u);
}
__device__ inline short bf_top(float v) {
    return (short)(__float_as_uint(v) >> 16);
}

// Gather top 16 bits of 8 floats into a bf16x8: 4 x v_perm_b32.
__device__ inline bf16x8 pack_top8(const float f[8]) {
    union { uint32_t u[4]; bf16x8 v; } r;
#pragma unroll
    for (int i = 0; i < 4; ++i)
        r.u[i] = __builtin_amdgcn_perm(__float_as_uint(f[2 * i + 1]),
                                       __float_as_uint(f[2 * i]), 0x07060302u);
    return r.v;
}

// d_ws layout (shorts): [0) w0'hi  [1024) w0'lo  [2048) w1s hi  [3072) w1s lo
//                       [4096) wos (rows >=2 zero)
// floats at byte 10240: bs0[32], bs1[32], bso[32]

__global__ void armint_prep(const float* __restrict__ w0, const float* __restrict__ b0,
                            const float* __restrict__ w1, const float* __restrict__ b1,
                            const float* __restrict__ wo, const float* __restrict__ bo,
                            short* __restrict__ ws, float* __restrict__ bsf)
{
    int t = threadIdx.x;
    for (int i = t; i < 1024; i += 256) {
        int n = i >> 5, k = i & 31;
        float diag = (n == k) ? 256.0f : 0.0f;

        float a = w0[i] + diag;                       // W0' (unscaled)
        ws[i]        = bf_top(a);
        ws[1024 + i] = bf_top(a - bf_topf(a));        // nonzero only near diagonal

        float b = (w1[i] + diag) * (1.0f / 256.0f);   // W1s (exact pow2 scale)
        ws[2048 + i] = bf_top(b);
        ws[3072 + i] = bf_top(b - bf_topf(b));

        float c = (n < 2) ? wo[n * 32 + k] * (1.0f / 256.0f) : 0.0f;
        ws[4096 + i] = bf_top(c);                     // small ints/256: exact
    }
    if (t < 32) {
        bsf[t]      = (b0[t] + 128.0f) * (1.0f / 256.0f);
        bsf[32 + t] = (b1[t] + 128.0f) * (1.0f / 256.0f);
        bsf[64 + t] = (t < 2) ? bo[t] * (1.0f / 256.0f) : 0.0f;
    }
}

__global__ __launch_bounds__(256)
void armint_mfma(const float* __restrict__ x, const short* __restrict__ ws,
                 const float* __restrict__ bias, float* __restrict__ out, int nrows)
{
    __shared__ float lds_all[4][2][32 * 36];

    const int lane = threadIdx.x & 63;
    const int wave = threadIdx.x >> 6;
    const int lm   = lane & 15;
    const int quad = lane >> 4;

    const size_t nn = (size_t)nrows;
    const size_t wbase = (size_t)blockIdx.x * 256 + (size_t)wave * 64;

    // ---------------- preprocessed weight/bias fragments ----------------
    bf16x8 w0hi[2], w0lo[2], w1hi[2], w1lo[2], wof;
    float bs0[2], bs1[2];
#pragma unroll
    for (int hh = 0; hh < 2; ++hh) {
        const int n = lm + 16 * hh;
        const int o = n * 32 + quad * 8;
        w0hi[hh] = *(const bf16x8*)(ws + o);
        w0lo[hh] = *(const bf16x8*)(ws + 1024 + o);
        w1hi[hh] = *(const bf16x8*)(ws + 2048 + o);
        w1lo[hh] = *(const bf16x8*)(ws + 3072 + o);
        bs0[hh] = bias[n];
        bs1[hh] = bias[32 + n];
    }
    wof = *(const bf16x8*)(ws + 4096 + lm * 32 + quad * 8);
    const float bsov = bias[64 + lm];

    // ---------------- load x for both tiles (latency overlapped) ----------------
    float4 xv[2][2][2];                               // [tile][t][half]
#pragma unroll
    for (int p = 0; p < 2; ++p)
#pragma unroll
        for (int t = 0; t < 2; ++t) {
            const float* xp = x + (wbase + (size_t)(p * 32 + t * 16 + lm)) * 32 + quad * 8;
            xv[p][t][0] = *(const float4*)xp;
            xv[p][t][1] = *(const float4*)(xp + 4);
        }

    // ---------------- exact 2-chunk split of x ----------------
    bf16x8 a0[2][2], a1[2][2];
#pragma unroll
    for (int p = 0; p < 2; ++p)
#pragma unroll
        for (int t = 0; t < 2; ++t) {
            float h[8] = {xv[p][t][0].x, xv[p][t][0].y, xv[p][t][0].z, xv[p][t][0].w,
                          xv[p][t][1].x, xv[p][t][1].y, xv[p][t][1].z, xv[p][t][1].w};
            a0[p][t] = pack_top8(h);
            float r[8];
#pragma unroll
            for (int j = 0; j < 8; ++j) r[j] = h[j] - bf_topf(h[j]);
            a1[p][t] = pack_top8(r);
        }

    // ---------------- layer 0 (residual via W' diagonal) ----------------
    f32x4 acc[2][2][2];
#pragma unroll
    for (int p = 0; p < 2; ++p)
#pragma unroll
        for (int t = 0; t < 2; ++t)
#pragma unroll
            for (int hh = 0; hh < 2; ++hh) {
                f32x4 c = {bs0[hh], bs0[hh], bs0[hh], bs0[hh]};
                c = MFMA16(a0[p][t], w0hi[hh], c);
                c = MFMA16(a1[p][t], w0hi[hh], c);
                c = MFMA16(a0[p][t], w0lo[hh], c);   // a1*W0lo dropped (diag-only, tiny)
                acc[p][t][hh] = c;
            }
#pragma unroll
    for (int p = 0; p < 2; ++p)
#pragma unroll
        for (int t = 0; t < 2; ++t)
#pragma unroll
            for (int hh = 0; hh < 2; ++hh)
#pragma unroll
                for (int k = 0; k < 4; ++k)
                    lds_all[wave][p][(t * 16 + quad * 4 + k) * 36 + lm + 16 * hh] =
                        fmaxf(truncf(acc[p][t][hh][k]), 0.0f);

    // ---------------- layer 1: reload A-layout, 2-chunk split ----------------
    bf16x8 c0[2][2], c1[2][2];
#pragma unroll
    for (int p = 0; p < 2; ++p)
#pragma unroll
        for (int t = 0; t < 2; ++t) {
            const int base = (t * 16 + lm) * 36 + quad * 8;
            float4 v0 = *(float4*)&lds_all[wave][p][base];
            float4 v1 = *(float4*)&lds_all[wave][p][base + 4];
            float h[8] = {v0.x, v0.y, v0.z, v0.w, v1.x, v1.y, v1.z, v1.w};
            c0[p][t] = pack_top8(h);
            float r[8];
#pragma unroll
            for (int j = 0; j < 8; ++j) r[j] = h[j] - bf_topf(h[j]);
            c1[p][t] = pack_top8(r);
        }
#pragma unroll
    for (int p = 0; p < 2; ++p)
#pragma unroll
        for (int t = 0; t < 2; ++t)
#pragma unroll
            for (int hh = 0; hh < 2; ++hh) {
                f32x4 c = {bs1[hh], bs1[hh], bs1[hh], bs1[hh]};
                c = MFMA16(c0[p][t], w1hi[hh], c);
                c = MFMA16(c1[p][t], w1hi[hh], c);
                c = MFMA16(c0[p][t], w1lo[hh], c);   // c1*W1lo dropped (diag-only, tiny)
                acc[p][t][hh] = c;
            }
#pragma unroll
    for (int p = 0; p < 2; ++p)
#pragma unroll
        for (int t = 0; t < 2; ++t)
#pragma unroll
            for (int hh = 0; hh < 2; ++hh)
#pragma unroll
                for (int k = 0; k < 4; ++k)
                    lds_all[wave][p][(t * 16 + quad * 4 + k) * 36 + lm + 16 * hh] =
                        fmaxf(truncf(acc[p][t][hh][k]), 0.0f);

    // ---------------- output layer ----------------
#pragma unroll
    for (int p = 0; p < 2; ++p)
#pragma unroll
        for (int t = 0; t < 2; ++t) {
            const int base = (t * 16 + lm) * 36 + quad * 8;
            float4 v0 = *(float4*)&lds_all[wave][p][base];
            float4 v1 = *(float4*)&lds_all[wave][p][base + 4];
            float h[8] = {v0.x, v0.y, v0.z, v0.w, v1.x, v1.y, v1.z, v1.w};
            bf16x8 d0 = pack_top8(h);
            float r[8];
#pragma unroll
            for (int j = 0; j < 8; ++j) r[j] = h[j] - bf_topf(h[j]);
            bf16x8 d1 = pack_top8(r);

            f32x4 c = {bsov, bsov, bsov, bsov};
            c = MFMA16(d0, wof, c);
            c = MFMA16(d1, wof, c);

            float o[4];
#pragma unroll
            for (int k = 0; k < 4; ++k) {
                float a = c[k];                       // = xx/256, exact
                o[k] = truncf(a + copysignf(0.5f, a)) * (1.0f / 256.0f);
            }
            const size_t row = wbase + (size_t)(p * 32 + t * 16 + quad * 4);
            if (lm == 0) {                            // mu
                *(float4*)(out + row) = make_float4(o[0], o[1], o[2], o[3]);
            }
            if (lm == 1) {                            // log_scale + scale
                *(float4*)(out + 2 * nn + row) = make_float4(o[0], o[1], o[2], o[3]);
                float s[4];
#pragma unroll
                for (int k = 0; k < 4; ++k)
                    s[k] = expf(fminf(fmaxf(o[k] - 4.0f, -4.6f), 5.0f));
                *(float4*)(out + nn + row) = make_float4(s[0], s[1], s[2], s[3]);
            }
        }
}

extern "C" void kernel_launch(void* const* d_in, const int* in_sizes, int n_in,
                              void* d_out, int out_size, void* d_ws, size_t ws_size,
                              hipStream_t stream) {
    const float* x  = (const float*)d_in[0];
    const float* w0 = (const float*)d_in[1];
    const float* b0 = (const float*)d_in[2];
    const float* w1 = (const float*)d_in[3];
    const float* b1 = (const float*)d_in[4];
    const float* wo = (const float*)d_in[5];
    const float* bo = (const float*)d_in[6];
    float* out = (float*)d_out;

    short* ws  = (short*)d_ws;
    float* bsf = (float*)((char*)d_ws + 10240);

    int nrows = in_sizes[0] / 32;             // B = 2097152, multiple of 256
    int grid = nrows / 256;                   // 64 rows/wave x 4 waves/block

    armint_prep<<<1, 256, 0, stream>>>(w0, b0, w1, b1, wo, bo, ws, bsf);
    armint_mfma<<<grid, 256, 0, stream>>>(x, ws, bsf, out, nrows);
}